// Round 10
// baseline (412.650 us; speedup 1.0000x reference)
//
#include <hip/hip_runtime.h>

#define BB 2
#define NN 512
#define DD 64
#define LN_EPS 1e-5f
#define NEG_SLOPE 0.01f
#define NPROD (BB * NN + BB)
#define SPIN_LIMIT 50000

typedef float f32x4 __attribute__((ext_vector_type(4)));

__device__ __forceinline__ float wave_reduce_sum(float v) {
    #pragma unroll
    for (int off = 32; off >= 1; off >>= 1)
        v += __shfl_xor(v, off, 64);
    return v;
}

__device__ __forceinline__ float wave_reduce_max(float v) {
    #pragma unroll
    for (int off = 32; off >= 1; off >>= 1)
        v = fmaxf(v, __shfl_xor(v, off, 64));
    return v;
}

__device__ __forceinline__ float reduce16(float v) {
    v += __shfl_xor(v, 1, 64);
    v += __shfl_xor(v, 2, 64);
    v += __shfl_xor(v, 4, 64);
    v += __shfl_xor(v, 8, 64);
    return v;
}

// Single dispatch, 2048 blocks x 256 threads. Block bid handles (row=bid>>1,
// half=bid&1): [embedded precompute (bid<1026, wave0)] -> out1 stream (64KB)
// -> acquire ws scalars (flag spin; fallback self-compute on timeout)
// -> softmax -> out0 stream (64KB).
__global__ __launch_bounds__(256) void fused_one_kernel(
    const float* __restrict__ ua,
    const float* __restrict__ iid,
    const float* __restrict__ ln_g,
    const float* __restrict__ ln_b,
    const float* __restrict__ w_att,
    const float* __restrict__ b_att,
    float* __restrict__ sq,
    float* __restrict__ sk,
    float* __restrict__ cb,
    unsigned* __restrict__ flag,
    float* __restrict__ out0,
    float* __restrict__ out1) {
    __shared__ float alpha_sh[256];
    __shared__ float red_mx[4];
    __shared__ float red_sm[4];
    __shared__ int ready_sh;
    // fallback-only storage
    __shared__ float gwk_sh[DD];
    __shared__ float sk_sh[NN];
    __shared__ float scal_sh[2];
    __shared__ float sqc_sh[2];

    const int bid2 = blockIdx.x;
    const int tid = threadIdx.x;
    const int row = bid2 >> 1;         // b*N + i
    const int half = bid2 & 1;
    const int b = row >> 9;
    const int i = row & (NN - 1);

    // ---- embedded precompute (wave 0 of blocks 0..NPROD-1) ----
    if (tid < 64 && bid2 < NPROD) {
        const int lane = tid;
        const float g = ln_g[lane];
        const float bet = ln_b[lane];
        if (bid2 < BB * NN) {
            float x = ua[bid2 * DD + lane];
            float m = wave_reduce_sum(x) * (1.0f / DD);
            float xc = x - m;
            float var = wave_reduce_sum(xc * xc) * (1.0f / DD);
            float r = rsqrtf(var + LN_EPS);
            float w = xc * r * g + bet;
            float s1 = wave_reduce_sum(w * w_att[lane]);
            float s2 = wave_reduce_sum(w * w_att[DD + lane]);
            if (lane == 0) {
                sq[bid2] = s1;
                sk[bid2] = s2;
            }
        } else {
            int bb = bid2 - BB * NN;
            float x = iid[bb * DD + lane];
            float m = wave_reduce_sum(x) * (1.0f / DD);
            float xc = x - m;
            float var = wave_reduce_sum(xc * xc) * (1.0f / DD);
            float r = rsqrtf(var + LN_EPS);
            float w = xc * r * g + bet;
            float s3 = wave_reduce_sum(w * w_att[2 * DD + lane]);
            if (lane == 0) {
                cb[bb] = s3 + b_att[0];
            }
        }
        __threadfence();   // make ws writes device-visible before the flag
        if (lane == 0)
            __hip_atomic_fetch_add(flag, 1u, __ATOMIC_RELEASE,
                                   __HIP_MEMORY_SCOPE_AGENT);
    }

    // ---- out1 stream for (row, half): 64 KB, no ws dependency ----
    const f32x4* __restrict__ uaB = (const f32x4*)(ua + (size_t)b * NN * DD);
    const f32x4* __restrict__ uaH = uaB + (size_t)half * 256 * 16;
    const f32x4 ui = uaB[(size_t)i * 16 + (tid & 15)];

    f32x4* __restrict__ o1 =
        (f32x4*)(out1 + (size_t)row * NN * DD + (size_t)half * 256 * DD);

    #pragma unroll 4
    for (int k = 0; k < 16; ++k) {
        const int idx = tid + k * 256;
        o1[idx] = ui * uaH[idx];
    }

    // ---- acquire ws scalars ----
    if (tid == 0) {
        int spins = 0;
        unsigned v;
        while ((v = __hip_atomic_load(flag, __ATOMIC_ACQUIRE,
                                      __HIP_MEMORY_SCOPE_AGENT)) < NPROD &&
               spins < SPIN_LIMIT) {
            ++spins;
            __builtin_amdgcn_s_sleep(8);
        }
        ready_sh = (v >= (unsigned)NPROD);
    }
    __syncthreads();

    float skv0, skv1, sqi, c;
    if (ready_sh) {
        __threadfence();
        sqi = sq[row];
        c = cb[b];
        skv0 = sk[b * NN + tid];
        skv1 = sk[b * NN + tid + 256];
    } else {
        // fallback: self-compute (pathological scheduling only)
        const int d4 = tid & 15;
        const int rbase = tid >> 4;
        if (tid < 64) {
            const float g  = ln_g[tid];
            const float be = ln_b[tid];
            const float wq = w_att[tid];
            const float wk = w_att[DD + tid];
            gwk_sh[tid] = g * wk;
            const float sgk = wave_reduce_sum(g * wk);
            const float sbk = wave_reduce_sum(be * wk);
            const float x = ua[row * DD + tid];
            const float m = wave_reduce_sum(x) * (1.0f / DD);
            const float xc = x - m;
            const float var = wave_reduce_sum(xc * xc) * (1.0f / DD);
            const float r = rsqrtf(var + LN_EPS);
            const float w = xc * r * g + be;
            const float sv = wave_reduce_sum(w * wq);
            if (tid == 0) {
                scal_sh[0] = sgk;
                scal_sh[1] = sbk;
                sqc_sh[0] = sv;
            }
        } else if (tid < 128) {
            const int lane = tid - 64;
            const float g  = ln_g[lane];
            const float be = ln_b[lane];
            const float wi = w_att[2 * DD + lane];
            const float x = iid[b * DD + lane];
            const float m = wave_reduce_sum(x) * (1.0f / DD);
            const float xc = x - m;
            const float var = wave_reduce_sum(xc * xc) * (1.0f / DD);
            const float r = rsqrtf(var + LN_EPS);
            const float s3 = wave_reduce_sum((xc * r * g + be) * wi);
            if (lane == 0) sqc_sh[1] = s3 + b_att[0];
        }
        __syncthreads();
        const float sgk = scal_sh[0], sbk = scal_sh[1];
        const f32x4 gk4 = ((const f32x4*)gwk_sh)[d4];
        #pragma unroll 4
        for (int it = 0; it < 32; ++it) {
            const int j = rbase + it * 16;
            const f32x4 x = uaB[j * 16 + d4];
            float psx  = x.x + x.y + x.z + x.w;
            float psxx = x.x * x.x + x.y * x.y + x.z * x.z + x.w * x.w;
            float pak  = x.x * gk4.x + x.y * gk4.y + x.z * gk4.z + x.w * gk4.w;
            psx = reduce16(psx);
            psxx = reduce16(psxx);
            pak = reduce16(pak);
            const float m = psx * (1.0f / DD);
            const float var = psxx * (1.0f / DD) - m * m;
            const float r = rsqrtf(var + LN_EPS);
            if (d4 == 0) sk_sh[j] = r * (pak - m * sgk) + sbk;
        }
        __syncthreads();
        sqi = sqc_sh[0];
        c = sqc_sh[1];
        skv0 = sk_sh[tid];
        skv1 = sk_sh[tid + 256];
    }

    // ---- softmax over 512 ----
    float s0 = sqi + skv0 + c;
    float s1 = sqi + skv1 + c;
    s0 = fmaxf(s0, NEG_SLOPE * s0);
    s1 = fmaxf(s1, NEG_SLOPE * s1);

    float mx = fmaxf(s0, s1);
    mx = wave_reduce_max(mx);
    const int wid = tid >> 6;
    if ((tid & 63) == 0) red_mx[wid] = mx;
    __syncthreads();
    mx = fmaxf(fmaxf(red_mx[0], red_mx[1]), fmaxf(red_mx[2], red_mx[3]));

    const float e0 = __expf(s0 - mx);
    const float e1 = __expf(s1 - mx);
    float sm = wave_reduce_sum(e0 + e1);
    if ((tid & 63) == 0) red_sm[wid] = sm;
    __syncthreads();
    sm = red_sm[0] + red_sm[1] + red_sm[2] + red_sm[3];
    const float inv = 1.0f / sm;

    alpha_sh[tid] = (half ? e1 : e0) * inv;
    __syncthreads();

    // ---- out0 stream for (row, half): 64 KB ----
    f32x4* __restrict__ o0 =
        (f32x4*)(out0 + (size_t)row * NN * DD + (size_t)half * 256 * DD);

    #pragma unroll 4
    for (int k = 0; k < 16; ++k) {
        const int idx = tid + k * 256;
        const float a = alpha_sh[idx >> 4];
        f32x4 av;
        av.x = a; av.y = a; av.z = a; av.w = a;
        o0[idx] = av;
    }
}

extern "C" void kernel_launch(void* const* d_in, const int* in_sizes, int n_in,
                              void* d_out, int out_size, void* d_ws, size_t ws_size,
                              hipStream_t stream) {
    const float* ua    = (const float*)d_in[0];
    const float* iid   = (const float*)d_in[1];
    const float* ln_g  = (const float*)d_in[2];
    const float* ln_b  = (const float*)d_in[3];
    const float* w_att = (const float*)d_in[4];
    const float* b_att = (const float*)d_in[5];

    float* out0 = (float*)d_out;                                // alphas [B,N,N,D]
    float* out1 = out0 + (size_t)BB * NN * NN * DD;             // value  [B,N,N,D]

    float* sq = (float*)d_ws;          // B*N
    float* sk = sq + BB * NN;          // B*N
    float* cb = sk + BB * NN;          // B
    unsigned* flag = (unsigned*)(cb + BB);

    hipMemsetAsync(flag, 0, sizeof(unsigned), stream);

    fused_one_kernel<<<BB * NN * 2, 256, 0, stream>>>(
        ua, iid, ln_g, ln_b, w_att, b_att, sq, sk, cb, flag, out0, out1);
}

// Round 11
// 49.022 us; speedup vs baseline: 8.4176x; 8.4176x over previous
//
#include <hip/hip_runtime.h>

#define BB 2
#define NN 512
#define DD 64
#define LN_EPS 1e-5f
#define NEG_SLOPE 0.01f

typedef float f32x4 __attribute__((ext_vector_type(4)));

__device__ __forceinline__ float wave_reduce_sum(float v) {
    #pragma unroll
    for (int off = 32; off >= 1; off >>= 1)
        v += __shfl_xor(v, off, 64);
    return v;
}

__device__ __forceinline__ float wave_reduce_max(float v) {
    #pragma unroll
    for (int off = 32; off >= 1; off >>= 1)
        v = fmaxf(v, __shfl_xor(v, off, 64));
    return v;
}

// K1: streams out1 = ua_i * ua_j (no precompute dependency). Wave 0 of the
// first 1026 blocks additionally computes sq/sk (ua rows) or c (iid rows)
// into d_ws — hidden under the store stream.
__global__ __launch_bounds__(256) void value_kernel(
    const float* __restrict__ ua,
    const float* __restrict__ iid,
    const float* __restrict__ ln_g,
    const float* __restrict__ ln_b,
    const float* __restrict__ w_att,
    const float* __restrict__ b_att,
    float* __restrict__ sq,
    float* __restrict__ sk,
    float* __restrict__ cb,
    float* __restrict__ out1) {
    const int bid2 = blockIdx.x;
    const int tid = threadIdx.x;

    // ---- embedded precompute (wave 0, blocks 0..BB*NN+BB-1) ----
    if (tid < 64 && bid2 < BB * NN + BB) {
        const int lane = tid;
        const float g = ln_g[lane];
        const float bet = ln_b[lane];
        if (bid2 < BB * NN) {
            float x = ua[bid2 * DD + lane];
            float m = wave_reduce_sum(x) * (1.0f / DD);
            float xc = x - m;
            float var = wave_reduce_sum(xc * xc) * (1.0f / DD);
            float r = rsqrtf(var + LN_EPS);
            float w = xc * r * g + bet;
            float s1 = wave_reduce_sum(w * w_att[lane]);
            float s2 = wave_reduce_sum(w * w_att[DD + lane]);
            if (lane == 0) {
                sq[bid2] = s1;
                sk[bid2] = s2;
            }
        } else {
            int b = bid2 - BB * NN;
            float x = iid[b * DD + lane];
            float m = wave_reduce_sum(x) * (1.0f / DD);
            float xc = x - m;
            float var = wave_reduce_sum(xc * xc) * (1.0f / DD);
            float r = rsqrtf(var + LN_EPS);
            float w = xc * r * g + bet;
            float s3 = wave_reduce_sum(w * w_att[2 * DD + lane]);
            if (lane == 0) {
                cb[b] = s3 + b_att[0];
            }
        }
    }

    // ---- stream out1 for (row, half) ----
    const int row = bid2 >> 1;         // b*N + i
    const int half = bid2 & 1;
    const int b = row >> 9;
    const int i = row & (NN - 1);

    const f32x4* __restrict__ uaB = (const f32x4*)(ua + (size_t)b * NN * DD);
    const f32x4* __restrict__ uaH = uaB + (size_t)half * 256 * 16;
    const f32x4 ui = uaB[(size_t)i * 16 + (tid & 15)];

    f32x4* __restrict__ o1 =
        (f32x4*)(out1 + (size_t)row * NN * DD + (size_t)half * 256 * DD);

    #pragma unroll 4
    for (int k = 0; k < 16; ++k) {
        const int idx = tid + k * 256;   // d4 = idx&15 == tid&15
        o1[idx] = ui * uaH[idx];
    }
}

// K2: softmax from ws scalars, then pure alpha-broadcast store stream.
__global__ __launch_bounds__(256) void alpha_kernel(
    const float* __restrict__ sq,
    const float* __restrict__ sk,
    const float* __restrict__ cb,
    float* __restrict__ out0) {
    __shared__ float alpha_sh[256];
    __shared__ float red_mx[4];
    __shared__ float red_sm[4];

    const int bid2 = blockIdx.x;
    const int row = bid2 >> 1;
    const int half = bid2 & 1;
    const int b = row >> 9;
    const int tid = threadIdx.x;

    const float sqi = sq[row];
    const float c = cb[b];

    float s0 = sqi + sk[b * NN + tid] + c;
    float s1 = sqi + sk[b * NN + tid + 256] + c;
    s0 = fmaxf(s0, NEG_SLOPE * s0);
    s1 = fmaxf(s1, NEG_SLOPE * s1);

    float mx = fmaxf(s0, s1);
    mx = wave_reduce_max(mx);
    const int wid = tid >> 6;
    if ((tid & 63) == 0) red_mx[wid] = mx;
    __syncthreads();
    mx = fmaxf(fmaxf(red_mx[0], red_mx[1]), fmaxf(red_mx[2], red_mx[3]));

    const float e0 = __expf(s0 - mx);
    const float e1 = __expf(s1 - mx);
    float sm = wave_reduce_sum(e0 + e1);
    if ((tid & 63) == 0) red_sm[wid] = sm;
    __syncthreads();
    sm = red_sm[0] + red_sm[1] + red_sm[2] + red_sm[3];
    const float inv = 1.0f / sm;

    alpha_sh[tid] = (half ? e1 : e0) * inv;
    __syncthreads();

    f32x4* __restrict__ o0 =
        (f32x4*)(out0 + (size_t)row * NN * DD + (size_t)half * 256 * DD);

    #pragma unroll 4
    for (int k = 0; k < 16; ++k) {
        const int idx = tid + k * 256;
        const float a = alpha_sh[idx >> 4];
        f32x4 av;
        av.x = a; av.y = a; av.z = a; av.w = a;
        o0[idx] = av;
    }
}

extern "C" void kernel_launch(void* const* d_in, const int* in_sizes, int n_in,
                              void* d_out, int out_size, void* d_ws, size_t ws_size,
                              hipStream_t stream) {
    const float* ua    = (const float*)d_in[0];
    const float* iid   = (const float*)d_in[1];
    const float* ln_g  = (const float*)d_in[2];
    const float* ln_b  = (const float*)d_in[3];
    const float* w_att = (const float*)d_in[4];
    const float* b_att = (const float*)d_in[5];

    float* out0 = (float*)d_out;                                // alphas [B,N,N,D]
    float* out1 = out0 + (size_t)BB * NN * NN * DD;             // value  [B,N,N,D]

    float* sq = (float*)d_ws;          // B*N
    float* sk = sq + BB * NN;          // B*N
    float* cb = sk + BB * NN;          // B

    value_kernel<<<BB * NN * 2, 256, 0, stream>>>(ua, iid, ln_g, ln_b,
                                                  w_att, b_att, sq, sk, cb, out1);
    alpha_kernel<<<BB * NN * 2, 256, 0, stream>>>(sq, sk, cb, out0);
}